// Round 2
// baseline (225.082 us; speedup 1.0000x reference)
//
#include <hip/hip_runtime.h>

// LatticeFilter: step-up (Levinson-Durbin) recursion, rc -> LPC coeffs.
//   rc: (B=16, p=128, Tf=8192) fp32, k_i = 0.98*rc[b,i,t]
//   out: (B, Tf, p+1=129) fp32, a[...,0]=1
//
// R7 theory. R6 post-mortem killed the AGPR-shuttle theory: VGPR=132 with
// FETCH/WRITE == exact input/output -> fully register-resident at the true
// live-set size. Absolute VALU-busy is ~28us in BOTH R5 and R6 (invariant
// across occupancy) -> it tracks instruction count: either the derived
// VALUBusy 2x-overcounts on SIMD-32 (true issue = 13.8us FMA floor, kernel
// is latency/front-end bound) or the front-end can't stream ~65KB of
// straight-line VOP3 text (8128 x 8B v_fma per wave) through the I$ at
// 1 instr/2cyc. Either way the same fix applies:
//
// PACK 2 COLUMNS PER LANE as float2 -> v_pk_fma_f32 (gfx90a+ packed fp32):
//  - instruction count halves: 4064 packed ops per TWO columns
//    -> per-SIMD issue for whole grid ~8.6us (vs 27.6us scalar-equiv)
//  - code size halves: ~65KB -> ~33KB, inside I$ reach
//  - per-column FMA order bit-identical (packing is across columns)
//  - state: A[1..128] float2 = 256 regs + PD=8 ring -> 1 wave/SIMD at the
//    512-reg unified budget. OK now: the serial compute chain also halved
//    (R6's failure was 2x13.8us serial SCALAR compute, not 1-wave per se).
//  - emitted via __builtin_elementwise_fma on ext_vector(2) -> llvm.fma.v2f32
//    -> V_PK_FMA_F32 (compile-safe; if backend scalarizes we fall back to
//    exactly the current scalar behavior and counters will show it).
// Lane i handles columns t and t+64 (+64 split keeps each epilogue round's
// output one contiguous 16B-aligned 33KB block).

#define NB   16
#define ORD  128
#define TF   8192
#define PD   8    // k prefetch ring depth (power of 2), 8 float2 = 16 VGPRs

typedef __attribute__((ext_vector_type(2))) float v2f;

static __device__ __forceinline__ v2f vfma(v2f a, v2f b, v2f c) {
    return __builtin_elementwise_fma(a, b, c);   // llvm.fma.v2f32 -> v_pk_fma_f32
}

// ---- pair update j <-> m-j, both columns, pre-step values (tmp-swap) ----
template<int M, int J>
struct PairUpd {
    static __device__ __forceinline__ void run(v2f (&A)[ORD + 1], v2f kk) {
        const v2f lo = A[J];
        const v2f hi = A[M - J];
        A[J]     = vfma(kk, hi, lo);
        A[M - J] = vfma(kk, lo, hi);
        if constexpr (2 * (J + 1) < M) PairUpd<M, J + 1>::run(A, kk);
    }
};

template<int M>
struct Step {
    static __device__ __forceinline__ void run(v2f (&A)[ORD + 1],
                                               v2f (&kq)[PD],
                                               const float* __restrict__ rcp) {
        constexpr int slot = (M - 1) & (PD - 1);
        const v2f kk = kq[slot] * 0.98f;
        if constexpr (M - 1 + PD < ORD) {        // refill slot for step M+PD
            v2f nk;
            nk.x = rcp[(size_t)(M - 1 + PD) * TF];        // column t
            nk.y = rcp[(size_t)(M - 1 + PD) * TF + 64];   // column t+64
            kq[slot] = nk;
        }
        asm volatile("" ::: "memory");            // throttle: <= PD pairs in flight
        if constexpr (M > 2) PairUpd<M, 1>::run(A, kk);
        if constexpr ((M & 1) == 0) {             // middle element self-update
            const v2f mid = A[M / 2];
            A[M / 2] = vfma(kk, mid, mid);
        }
        A[M] = kk;                                // a[0] == 1 contributes k
        if constexpr (M < ORD) Step<M + 1>::run(A, kq, rcp);
    }
};

// ---- LDS staging of one column-half (H=0 -> .x, H=1 -> .y), static idx ----
template<int J, int H>
struct Stage {
    static __device__ __forceinline__ void run(float* __restrict__ dst,
                                               const v2f (&A)[ORD + 1]) {
        dst[J] = (H == 0) ? A[J].x : A[J].y;
        if constexpr (J < ORD) Stage<J + 1, H>::run(dst, A);
    }
};

__global__ __launch_bounds__(64)
__attribute__((amdgpu_waves_per_eu(1, 1)))
void lpc_stepup_kernel(const float* __restrict__ rc, float* __restrict__ out) {
    const int lane = threadIdx.x;                 // 0..63, one wave per block
    const int col0 = blockIdx.x * 128 + lane;     // lane's first column; 2nd = +64
    const int b = col0 >> 13;                     // col0 / TF (uniform per block)
    const int t = col0 & (TF - 1);                // col0 % TF
    const float* rcp = rc + ((size_t)b * ORD) * TF + t;

    // ---- prime the k ring: 2x PD coalesced dword loads ----
    v2f kq[PD];
#pragma unroll
    for (int i = 0; i < PD; ++i) {
        v2f nk;
        nk.x = rcp[(size_t)i * TF];
        nk.y = rcp[(size_t)i * TF + 64];
        kq[i] = nk;
    }

    v2f A[ORD + 1];
    A[0] = (v2f){1.0f, 1.0f};
    Step<1>::run(A, kq, rcp);                     // straight-line, packed, reg-resident

    // ---- epilogue: 2 rounds of 64 rows x 129 cols through LDS ----
    // stage: bank stride 1 (129 mod 32 = 1) -> free 2-way wave64 aliasing
    // store: 2064 contiguous float4 per round, 33024B blocks (16B aligned)
    __shared__ __align__(16) float lds[64 * (ORD + 1)];   // 33,024 B
    float* out_block = out + (size_t)blockIdx.x * 128 * (ORD + 1);

    Stage<0, 0>::run(&lds[lane * (ORD + 1)], A);  // rows = columns t..t+63
    __syncthreads();
    {
        const float4* lds4 = (const float4*)lds;
        float4* out4 = (float4*)out_block;
#pragma unroll 4
        for (int e = lane; e < (64 * (ORD + 1)) / 4; e += 64)
            out4[e] = lds4[e];                    // perfectly coalesced
    }
    __syncthreads();
    Stage<0, 1>::run(&lds[lane * (ORD + 1)], A);  // rows = columns t+64..t+127
    __syncthreads();
    {
        const float4* lds4 = (const float4*)lds;
        float4* out4 = (float4*)(out_block + 64 * (ORD + 1));
#pragma unroll 4
        for (int e = lane; e < (64 * (ORD + 1)) / 4; e += 64)
            out4[e] = lds4[e];
    }
}

extern "C" void kernel_launch(void* const* d_in, const int* in_sizes, int n_in,
                              void* d_out, int out_size, void* d_ws, size_t ws_size,
                              hipStream_t stream) {
    // d_in[0] = excitation (dead in reference), d_in[1] = rc
    const float* rc = (const float*)d_in[1];
    float* out = (float*)d_out;
    dim3 grid((NB * TF) / 128);   // 1024 one-wave blocks, 2 columns per lane
    dim3 block(64);
    hipLaunchKernelGGL(lpc_stepup_kernel, grid, block, 0, stream, rc, out);
}

// Round 3
// 173.283 us; speedup vs baseline: 1.2989x; 1.2989x over previous
//
#include <hip/hip_runtime.h>

// LatticeFilter: step-up (Levinson-Durbin) recursion, rc -> LPC coeffs.
//   rc: (B=16, p=128, Tf=8192) fp32, k_i = 0.98*rc[b,i,t]
//   out: (B, Tf, p+1=129) fp32, a[...,0]=1
//
// R8 theory. R7 post-mortem: (1) arch VGPRs cap at 256/lane -> packed
// 2-col state (256 regs + overhead) can never fit; allocator spilled to
// scratch (VGPR=148, 181us at 1 wave/SIMD). (2) Decisive: absolute VALU
// busy HALVED (14us vs 28us) -> v_pk_fma worked; and since R6 (fully
// register-resident, VGPR=132) also showed 2x my issue floor, the derived
// VALUBusy double-counts on SIMD-32. True busy ~14us of 52.8/71us wall:
// the VALU is ~75% idle in ALL kernels. Issue was never the bottleneck.
// Surviving theory: INSTRUCTION FETCH. The recursion is 8128 v_fma x 8B
// = 65KB straight-line code > L1I; every wave streams it from L2 with
// limited miss parallelism (~1000 lines x ~200cy / few in flight = tens
// of us) -- magnitude matches R5 (52.8) and R6 (71, 2 generations), and
// explains why TLP doesn't help (waves stall on the same front-end).
//
// Fix: SPLIT INTO TWO LAUNCHES at step S=52, partial state a[1..52]
// parked at its FINAL location in d_out (no ws-size gamble; each column's
// state slot == its output slot -> no cross-block races; fp32 store/load
// round-trip is exact, FMA order unchanged -> bit-identical results).
//   A (steps 1..52):  ~13KB code, fits ANY L1I. Live ~110 regs.
//   B (steps 53..128): ~57KB code, fits 64KB L1I. Live flat ~133
//     (52 state + 76 k's die exactly as a[] grows -- R6's proven shape).
// Cost: +55MB state round-trip (total ~160MB, BW floor ~25us).
// Clean experiment: if A hits its ~8us BW floor while B lags -> T-I$
// confirmed + L1I size diagnosed (3-way/hybrid next). If A is slow with
// 13KB code -> T-I$ refuted, pivot.

#define NB    16
#define ORD   128
#define TF    8192
#define SPLIT 52

// ---- pair update j <-> m-j, both reading pre-step values (tmp-swap) ----
template<int M, int J>
struct PairUpd {
    static __device__ __forceinline__ void run(float (&a)[ORD + 1], float k) {
        const float lo = a[J];
        const float hi = a[M - J];
        a[J]     = fmaf(k, hi, lo);
        a[M - J] = fmaf(k, lo, hi);
        if constexpr (2 * (J + 1) < M) PairUpd<M, J + 1>::run(a, k);
    }
};

// Steps M..MEND, k taken from kq[M-1-K0] (pre-scaled by 0.98 at load? no:
// scale here, loads stay raw dwords)
template<int M, int MEND, int K0, int NK>
struct Step {
    static __device__ __forceinline__ void run(float (&a)[ORD + 1],
                                               const float (&kq)[NK]) {
        const float k = 0.98f * kq[M - 1 - K0];
        if constexpr (M > 2) PairUpd<M, 1>::run(a, k);
        if constexpr ((M & 1) == 0) {            // middle element self-update
            const float mid = a[M / 2];
            a[M / 2] = fmaf(k, mid, mid);
        }
        a[M] = k;                                // a[0] == 1 contributes k
        if constexpr (M < MEND) Step<M + 1, MEND, K0, NK>::run(a, kq);
    }
};

// ---- LDS staging, static indices (compiler merges into ds_write_b128) ----
template<int J>
struct Stage {
    static __device__ __forceinline__ void run(float* __restrict__ dst,
                                               const float (&a)[ORD + 1]) {
        dst[J] = a[J];
        if constexpr (J < ORD) Stage<J + 1>::run(dst, a);
    }
};

// =======================  Kernel A: steps 1..SPLIT  =======================
// ~13KB code. Writes a[1..SPLIT] to out[col*129 + j] (final positions).
__global__ __launch_bounds__(256)
__attribute__((amdgpu_waves_per_eu(2, 2)))
void lpc_stepA(const float* __restrict__ rc, float* __restrict__ out) {
    const int col = blockIdx.x * 256 + threadIdx.x;   // flattened (B*Tf) column
    const int b = col >> 13;
    const int t = col & (TF - 1);
    const float* rcp = rc + ((size_t)b * ORD) * TF + t;

    float kq[SPLIT];                                  // full prefetch, flat pressure
#pragma unroll
    for (int i = 0; i < SPLIT; ++i) kq[i] = rcp[(size_t)i * TF];

    float a[ORD + 1];
    a[0] = 1.0f;
    Step<1, SPLIT, 0, SPLIT>::run(a, kq);

    // state -> final out positions; per-lane strided dword stores
    float* op = out + (size_t)col * (ORD + 1);
#pragma unroll
    for (int j = 1; j <= SPLIT; ++j) op[j] = a[j];
}

// =====================  Kernel B: steps SPLIT+1..128  =====================
// ~57KB code. Reads state back, finishes recursion, writes full rows via
// the proven conflict-free LDS transpose (stride 129 -> bank stride 1).
__global__ __launch_bounds__(128)
__attribute__((amdgpu_waves_per_eu(2, 2)))
void lpc_stepB(const float* __restrict__ rc, float* out) {
    const int tid = threadIdx.x;
    const int col = blockIdx.x * 128 + tid;
    const int b = col >> 13;
    const int t = col & (TF - 1);
    const float* rcp = rc + ((size_t)b * ORD) * TF + t;

    constexpr int NK = ORD - SPLIT;                   // 76 remaining k's
    float kq[NK];
#pragma unroll
    for (int i = 0; i < NK; ++i) kq[i] = rcp[(size_t)(SPLIT + i) * TF];

    float a[ORD + 1];
    a[0] = 1.0f;
    {   // reload state from final out positions (per-lane strided dwords)
        const float* op = out + (size_t)col * (ORD + 1);
#pragma unroll
        for (int j = 1; j <= SPLIT; ++j) a[j] = op[j];
    }

    Step<SPLIT + 1, ORD, SPLIT, NK>::run(a, kq);

    // ---- epilogue: transpose 128 rows x 129 cols through LDS, 2 rounds ----
    // stage: bank stride 1 (129 mod 32 = 1) -> free 2-way wave64 aliasing
    // store: 2064 contiguous float4 per round -> every 128B line written whole
    __shared__ __align__(16) float lds[64 * (ORD + 1)];   // 33,024 B
    const int my_round = tid >> 6;                    // wave index, uniform branch
    const int row      = tid & 63;

    for (int r = 0; r < 2; ++r) {
        __syncthreads();
        if (my_round == r)
            Stage<0>::run(&lds[row * (ORD + 1)], a);
        __syncthreads();
        const float4* lds4 = (const float4*)lds;
        float4* out4 = (float4*)(out + (size_t)(blockIdx.x * 128 + r * 64) * (ORD + 1));
#pragma unroll 4
        for (int e = tid; e < (64 * (ORD + 1)) / 4; e += 128)
            out4[e] = lds4[e];                        // perfectly coalesced
    }
}

extern "C" void kernel_launch(void* const* d_in, const int* in_sizes, int n_in,
                              void* d_out, int out_size, void* d_ws, size_t ws_size,
                              hipStream_t stream) {
    // d_in[0] = excitation (dead in reference), d_in[1] = rc
    const float* rc = (const float*)d_in[1];
    float* out = (float*)d_out;
    hipLaunchKernelGGL(lpc_stepA, dim3((NB * TF) / 256), dim3(256), 0, stream, rc, out);
    hipLaunchKernelGGL(lpc_stepB, dim3((NB * TF) / 128), dim3(128), 0, stream, rc, out);
}